// Round 6
// baseline (30.188 us; speedup 1.0000x reference)
//
#include <hip/hip_runtime.h>
#include <math.h>

#define DFEAT 50
#define BLOCK 256
#define WINU 24          // series terms above the peak
#define WIND 24          // series terms below the peak (self-clamps at j=0)

// C = 25*ln(2*pi) - 24*ln(2)  (kappa-independent constant in -log_cmk)
#define CADD 29.311394326794948f

// Stirling: lnGamma(x) = (x-.5)ln x - x + .5*ln(2pi) + 1/(12x) - 1/(360x^3)
// Peak args here are >= ~2 -> abs error <= ~2e-5 per row (mean over 524k rows).
__device__ __forceinline__ float lgamma_stirling(float x) {
    float lnx = logf(x);
    float inv = __builtin_amdgcn_rcpf(x);
    float inv2 = inv * inv;
    return fmaf(x - 0.5f, lnx, -x) + 0.91893853320467274f
         + inv * fmaf(-inv2, 1.0f / 360.0f, 1.0f / 12.0f);
}

// -log_cmk for one row given kappa (series around analytic peak, linear space)
__device__ __forceinline__ float nll_row(float kappa) {
    // T_j = (k/2)^(24+2j) / (j! * (j+24)!);  T_{j+1}/T_j = q/((j+1)(j+25))
    const float lhk = logf(0.5f * kappa);
    const float q = 0.25f * kappa * kappa;
    float jpk = floorf(sqrtf(144.0f + q) - 13.0f);   // peak index
    jpk = fmaxf(jpk, 0.0f);

    // absolute log (nats) of the peak term
    const float lt = fmaf(2.0f * jpk, lhk,
                          -lgamma_stirling(jpk + 1.0f) - lgamma_stirling(jpk + 25.0f));

    // upward chain: ratios <= 1 past the peak
    float su = 0.0f, u = 1.0f;
#pragma unroll
    for (int k = 0; k < WINU; ++k) {
        float a = (jpk + (float)(k + 1)) * (jpk + (float)(k + 25));
        u *= q * __builtin_amdgcn_rcpf(a);
        su += u;
    }

    // downward chain: factor contains j -> vanishes automatically below j=0
    float sd = 0.0f, d = 1.0f;
    const float invq = __builtin_amdgcn_rcpf(q);
#pragma unroll
    for (int k = 0; k < WIND; ++k) {
        float j = jpk - (float)k;
        d *= (j * (j + 24.0f)) * invq;
        sd += d;
    }

    // -log_cmk = ln(T_peak * S) + CADD  (V*log(kappa) terms cancel into CADD)
    return lt + logf(1.0f + su + sd) + CADD;
}

__global__ __launch_bounds__(BLOCK) void nll_partial(const float* __restrict__ in,
                                                     float* __restrict__ part) {
    __shared__ float wsum[BLOCK / 64];
    const int tid = threadIdx.x;
    const int t = blockIdx.x * BLOCK + tid;      // one thread per ROW PAIR

    // ---- 2 rows = 400B, 16B-aligned: 25 x float4, compile-time row split ----
    const float4* p = (const float4*)(in + (size_t)t * (2 * DFEAT));
    float k0 = 0.0f, k1 = 0.0f;
#pragma unroll
    for (int v = 0; v < 25; ++v) {
        float4 x = p[v];
        if (v < 12) {                            // flat 0..47 -> row0
            k0 += (fabsf(x.x) + fabsf(x.y)) + (fabsf(x.z) + fabsf(x.w));
        } else if (v == 12) {                    // flat 48,49 | 50,51
            k0 += fabsf(x.x) + fabsf(x.y);
            k1 += fabsf(x.z) + fabsf(x.w);
        } else {                                 // flat 52..99 -> row1
            k1 += (fabsf(x.x) + fabsf(x.y)) + (fabsf(x.z) + fabsf(x.w));
        }
    }

    // ---- two independent series (ILP: chains interleave in the scheduler) ----
    float v = nll_row(k0) + nll_row(k1);

    // ---- block reduction -> one partial per block (plain store, no init) ----
#pragma unroll
    for (int off = 32; off > 0; off >>= 1)
        v += __shfl_xor(v, off);
    if ((tid & 63) == 0) wsum[tid >> 6] = v;
    __syncthreads();
    if (tid == 0) {
        float b = 0.0f;
#pragma unroll
        for (int w = 0; w < BLOCK / 64; ++w) b += wsum[w];
        part[blockIdx.x] = b;
    }
}

// Reduce the block partials and write the mean. No memset anywhere.
__global__ __launch_bounds__(BLOCK) void nll_final(const float* __restrict__ part,
                                                   float* __restrict__ out,
                                                   int nblk, float inv_rows) {
    __shared__ float wsum[BLOCK / 64];
    const int tid = threadIdx.x;
    float v = 0.0f;
    const float4* p4 = (const float4*)part;      // nblk/4 float4s
    for (int i = tid; i < nblk / 4; i += BLOCK) {
        float4 a = p4[i];
        v += a.x + a.y + a.z + a.w;
    }
#pragma unroll
    for (int off = 32; off > 0; off >>= 1)
        v += __shfl_xor(v, off);
    if ((tid & 63) == 0) wsum[tid >> 6] = v;
    __syncthreads();
    if (tid == 0) {
        float b = 0.0f;
#pragma unroll
        for (int w = 0; w < BLOCK / 64; ++w) b += wsum[w];
        out[0] = b * inv_rows;
    }
}

extern "C" void kernel_launch(void* const* d_in, const int* in_sizes, int n_in,
                              void* d_out, int out_size, void* d_ws, size_t ws_size,
                              hipStream_t stream) {
    const float* in = (const float*)d_in[0];     // target (d_in[1]) unused by reference
    float* out = (float*)d_out;
    float* part = (float*)d_ws;                  // 1024 floats = 4 KB scratch
    const int rows = in_sizes[0] / DFEAT;        // 524288
    const int nblk = rows / (2 * BLOCK);         // 1024 (2 rows per thread)

    nll_partial<<<nblk, BLOCK, 0, stream>>>(in, part);
    nll_final<<<1, BLOCK, 0, stream>>>(part, out, nblk, 1.0f / (float)rows);
}

// Round 7
// 23.497 us; speedup vs baseline: 1.2847x; 1.2847x over previous
//
#include <hip/hip_runtime.h>
#include <math.h>

#define DFEAT 50
#define BLOCK 256
#define WINU 24          // series terms above the peak
#define WIND 24          // series terms below the peak (self-clamps at j=0)

// C = 25*ln(2*pi) - 24*ln(2)  (kappa-independent constant in -log_cmk)
#define CADD 29.311394326794948f

// Stirling: lnGamma(x) = (x-.5)ln x - x + .5*ln(2pi) + 1/(12x) - 1/(360x^3)
__device__ __forceinline__ float lgamma_stirling(float x) {
    float lnx = logf(x);
    float inv = __builtin_amdgcn_rcpf(x);
    float inv2 = inv * inv;
    return fmaf(x - 0.5f, lnx, -x) + 0.91893853320467274f
         + inv * fmaf(-inv2, 1.0f / 360.0f, 1.0f / 12.0f);
}

// -log_cmk for one row given kappa (series around analytic peak, linear space)
__device__ __forceinline__ float nll_row(float kappa) {
    // T_j = (k/2)^(24+2j) / (j! * (j+24)!);  T_{j+1}/T_j = q/((j+1)(j+25))
    const float lhk = logf(0.5f * kappa);
    const float q = 0.25f * kappa * kappa;
    float jpk = floorf(sqrtf(144.0f + q) - 13.0f);   // peak index
    jpk = fmaxf(jpk, 0.0f);

    // absolute log (nats) of the peak term
    const float lt = fmaf(2.0f * jpk, lhk,
                          -lgamma_stirling(jpk + 1.0f) - lgamma_stirling(jpk + 25.0f));

    // upward chain: ratios <= 1 past the peak
    float su = 0.0f, u = 1.0f;
#pragma unroll
    for (int k = 0; k < WINU; ++k) {
        float a = (jpk + (float)(k + 1)) * (jpk + (float)(k + 25));
        u *= q * __builtin_amdgcn_rcpf(a);
        su += u;
    }

    // downward chain: factor contains j -> vanishes automatically below j=0
    float sd = 0.0f, d = 1.0f;
    const float invq = __builtin_amdgcn_rcpf(q);
#pragma unroll
    for (int k = 0; k < WIND; ++k) {
        float j = jpk - (float)k;
        d *= (j * (j + 24.0f)) * invq;
        sd += d;
    }

    // -log_cmk = ln(T_peak * S) + CADD  (V*log(kappa) terms cancel into CADD)
    return lt + logf(1.0f + su + sd) + CADD;
}

__global__ __launch_bounds__(BLOCK) void nll_partial(const float* __restrict__ in,
                                                     float* __restrict__ part) {
    __shared__ float wsum[BLOCK / 64];
    const int tid = threadIdx.x;
    const int t = blockIdx.x * BLOCK + tid;      // one thread per row (8192 waves)

    // ---- paired float4 loads: thread pair splits its 400B row-pair ----
    // pair p = t>>1 owns float4s [25p, 25p+25). even thread: [25p, 25p+12]
    // (flat 0..51), odd: [25p+12, 25p+24] (flat 48..99); seam f4 #12 read by
    // both, each keeps its half. 13 aligned float4 loads, uniform, no shfl.
    const int e = t & 1;
    const float4* q = (const float4*)in + (25 * (t >> 1) + 12 * e);

    float s = 0.0f, a0 = 0.0f, b12 = 0.0f;
#pragma unroll
    for (int i = 0; i < 13; ++i) {
        float4 x = q[i];
        float axy = fabsf(x.x) + fabsf(x.y);
        float azw = fabsf(x.z) + fabsf(x.w);
        s += axy + azw;
        if (i == 0)  a0  = axy;   // flat +0,+1 (odd thread: flat 48,49 -> row0's)
        if (i == 12) b12 = azw;   // flat +50,+51 (even thread: flat 50,51 -> row1's)
    }
    const float kappa = s - (e ? a0 : b12);

    float v = nll_row(kappa);

    // ---- block reduction -> one partial per block (plain store, no init) ----
#pragma unroll
    for (int off = 32; off > 0; off >>= 1)
        v += __shfl_xor(v, off);
    if ((tid & 63) == 0) wsum[tid >> 6] = v;
    __syncthreads();
    if (tid == 0) {
        float b = 0.0f;
#pragma unroll
        for (int w = 0; w < BLOCK / 64; ++w) b += wsum[w];
        part[blockIdx.x] = b;
    }
}

// Reduce the block partials and write the mean. No memset anywhere.
__global__ __launch_bounds__(BLOCK) void nll_final(const float* __restrict__ part,
                                                   float* __restrict__ out,
                                                   int nblk, float inv_rows) {
    __shared__ float wsum[BLOCK / 64];
    const int tid = threadIdx.x;
    float v = 0.0f;
    const float4* p4 = (const float4*)part;      // nblk/4 float4s
    for (int i = tid; i < nblk / 4; i += BLOCK) {
        float4 a = p4[i];
        v += a.x + a.y + a.z + a.w;
    }
#pragma unroll
    for (int off = 32; off > 0; off >>= 1)
        v += __shfl_xor(v, off);
    if ((tid & 63) == 0) wsum[tid >> 6] = v;
    __syncthreads();
    if (tid == 0) {
        float b = 0.0f;
#pragma unroll
        for (int w = 0; w < BLOCK / 64; ++w) b += wsum[w];
        out[0] = b * inv_rows;
    }
}

extern "C" void kernel_launch(void* const* d_in, const int* in_sizes, int n_in,
                              void* d_out, int out_size, void* d_ws, size_t ws_size,
                              hipStream_t stream) {
    const float* in = (const float*)d_in[0];     // target (d_in[1]) unused by reference
    float* out = (float*)d_out;
    float* part = (float*)d_ws;                  // 2048 floats = 8 KB scratch
    const int rows = in_sizes[0] / DFEAT;        // 524288
    const int nblk = rows / BLOCK;               // 2048 -> 32 waves/CU (full)

    nll_partial<<<nblk, BLOCK, 0, stream>>>(in, part);
    nll_final<<<1, BLOCK, 0, stream>>>(part, out, nblk, 1.0f / (float)rows);
}